// Round 8
// baseline (299.684 us; speedup 1.0000x reference)
//
#include <hip/hip_runtime.h>
#include <hip/hip_fp16.h>
#include <math.h>

#define N_NODES 100000
#define N_EDGES 1200000
#define SLOTS   48                              // Poisson(12): P(any deg>48) ~ 3e-10
#define HEAD_BLOCKS ((N_NODES + 63) / 64)       // L2/L3 grid: 1563 blocks, 64 nodes
#define L1_BLOCKS  ((N_NODES + 255) / 256)      // L1 grid: 391 blocks, 256 nodes

// bucketed adjacency build (R19)
#define BNODES 256                              // nodes per bucket (dst>>8)
#define NBUCK  ((N_NODES + BNODES - 1) / BNODES)   // 391
#define BCAP   3584                             // 9.3 sigma above mean 3070
#define CHUNK  4096                             // edges per partition block

typedef _Float16 half8_t __attribute__((ext_vector_type(8)));
typedef float    f32x4_t __attribute__((ext_vector_type(4)));

// ---------------------------------------------------------------- utilities

__device__ __forceinline__ float bcastf(float v, int l) {
    return __uint_as_float(__builtin_amdgcn_readlane(__float_as_uint(v), (unsigned)l));
}

__device__ __forceinline__ void accum8(float* m, const uint4& v) {
    const __half2* p = reinterpret_cast<const __half2*>(&v);
#pragma unroll
    for (int t = 0; t < 4; ++t) {
        const float2 f = __half22float2(p[t]);
        m[2 * t] += f.x; m[2 * t + 1] += f.y;
    }
}

__device__ __forceinline__ void accum4(float* m, const uint2& v) {
    const __half2* p = reinterpret_cast<const __half2*>(&v);
    const float2 f0 = __half22float2(p[0]);
    const float2 f1 = __half22float2(p[1]);
    m[0] += f0.x; m[1] += f0.y; m[2] += f1.x; m[3] += f1.y;
}

// x -> padded fp16 [N+1][8]; + cursor zero + h-buffer sentinel rows zero
__global__ __launch_bounds__(256) void convert_init(const float* __restrict__ x,
                                                    __half* __restrict__ x16,
                                                    unsigned* __restrict__ cursor,
                                                    __half* __restrict__ zA,
                                                    __half* __restrict__ zB) {
    const int gid = blockIdx.x * 256 + threadIdx.x;
    if (gid <= N_NODES) {
        __half h[8];
#pragma unroll
        for (int i = 0; i < 8; ++i) h[i] = __float2half(0.f);
        if (gid < N_NODES) {
#pragma unroll
            for (int i = 0; i < 5; ++i) h[i] = __float2half(x[gid * 5 + i]);
        }
        *reinterpret_cast<uint4*>(&x16[(size_t)gid * 8]) =
            *reinterpret_cast<const uint4*>(h);
    }
    if (gid < NBUCK) cursor[gid] = 0u;
    if (gid < 64) {
        zA[(size_t)N_NODES * 64 + gid] = __float2half(0.f);
        zB[(size_t)N_NODES * 64 + gid] = __float2half(0.f);
    }
}

// ---------------------------------------------------------------- adjacency build
// Pass 1: partition edges into dst-range buckets (LDS histogram -> one cursor
// reservation per (block,bucket) -> run appends). R19-proven.
__global__ __launch_bounds__(256) void edge_partition(const int* __restrict__ src,
                                                      const int* __restrict__ dst,
                                                      unsigned* __restrict__ cursor,
                                                      unsigned* __restrict__ packed) {
    __shared__ unsigned histL[NBUCK];
    __shared__ unsigned baseL[NBUCK];
    const int tid = threadIdx.x;
    const int e0 = blockIdx.x * CHUNK;
    for (int b = tid; b < NBUCK; b += 256) histL[b] = 0u;
    __syncthreads();
#pragma unroll
    for (int i = 0; i < CHUNK / 256; ++i) {
        const int e = e0 + i * 256 + tid;
        if (e < N_EDGES) atomicAdd(&histL[(unsigned)dst[e] >> 8], 1u);
    }
    __syncthreads();
    for (int b = tid; b < NBUCK; b += 256) {
        const unsigned c = histL[b];
        baseL[b] = c ? atomicAdd(&cursor[b], c) : 0u;
        histL[b] = 0u;                           // reuse as local position counter
    }
    __syncthreads();
#pragma unroll
    for (int i = 0; i < CHUNK / 256; ++i) {
        const int e = e0 + i * 256 + tid;
        if (e < N_EDGES) {
            const unsigned d = (unsigned)dst[e], s = (unsigned)src[e];
            const unsigned b = d >> 8;
            const unsigned r = atomicAdd(&histL[b], 1u);
            const unsigned pos = baseL[b] + r;
            if (pos < BCAP)                       // astronomically-rare overflow guard
                packed[(size_t)b * BCAP + pos] = ((d & 255u) << 17) | s;
        }
    }
}

// Pass 2: one block per bucket; slot rows built in LDS, streamed out coalesced.
__global__ __launch_bounds__(256) void bucket_build(const unsigned* __restrict__ packed,
                                                    const unsigned* __restrict__ cursor,
                                                    unsigned* __restrict__ slots,
                                                    unsigned* __restrict__ cnt,
                                                    float* __restrict__ invcnt) {
    __shared__ __align__(16) unsigned slotsL[BNODES * SLOTS];   // 48 KB
    __shared__ unsigned cntL[BNODES];
    const int tid = threadIdx.x;
    const int b = blockIdx.x;
    cntL[tid] = 0u;
    __syncthreads();
    const unsigned nE = min(cursor[b], (unsigned)BCAP);
    const unsigned* pb = packed + (size_t)b * BCAP;
    for (unsigned i = tid; i < nE; i += 256) {
        const unsigned p = pb[i];
        const unsigned dl = p >> 17;
        const unsigned r = atomicAdd(&cntL[dl], 1u);
        if (r < SLOTS) slotsL[dl * SLOTS + r] = p & 0x1FFFFu;
    }
    __syncthreads();
    const int nvalid = min(N_NODES - b * BNODES, BNODES);
    const uint4* sl4 = reinterpret_cast<const uint4*>(slotsL);
    uint4* sg4 = reinterpret_cast<uint4*>(slots) + (size_t)b * (BNODES * SLOTS / 4);
    const int l4 = nvalid * (SLOTS / 4);
    for (int i = tid; i < l4; i += 256) sg4[i] = sl4[i];
    if (tid < nvalid) {
        const int node = b * BNODES + tid;
        const unsigned c = cntL[tid];
        cnt[node] = c;
        invcnt[node] = 1.0f / (float)(c + 1u);   // +1 self loop
    }
}

// ---------------------------------------------------------------- weight folding
// V2 = W @ U_bot [IN,64];  cp = c + b @ U_bot [64]
template <int IN>
__global__ __launch_bounds__(256) void precompute_v(const float* __restrict__ W,
                                                    const float* __restrict__ b,
                                                    const float* __restrict__ U,
                                                    const float* __restrict__ c,
                                                    float* __restrict__ V2,
                                                    float* __restrict__ cp) {
    __shared__ float Ub[64 * 64];
    const int tid = threadIdx.x;
    for (int j = tid; j < 64 * 64; j += 256) Ub[j] = U[IN * 64 + j];
    __syncthreads();
    const int w = tid >> 6, lane = tid & 63;
    const int r = blockIdx.x * 4 + w;
    if (r > IN) return;
    const float wv = (r < IN) ? W[r * 64 + lane] : b[lane];
    float o = (r < IN) ? 0.f : c[lane];
#pragma unroll 8
    for (int k = 0; k < 64; ++k) o += bcastf(wv, k) * Ub[k * 64 + lane];
    if (r < IN) V2[r * 64 + lane] = o;
    else        cp[lane] = o;
}

// Interleaved-transposed fp16 weights: BT[col][k], k=2q -> Utop[q][col],
// k=2q+1 -> V2[q][col].
__global__ __launch_bounds__(64) void bt_build(const float* __restrict__ U1,
                                               const float* __restrict__ V2a,
                                               const float* __restrict__ U2,
                                               const float* __restrict__ V2b,
                                               const float* __restrict__ U3,
                                               const float* __restrict__ V2c,
                                               __half* __restrict__ BTa,
                                               __half* __restrict__ BTb,
                                               __half* __restrict__ BTc) {
    const int b = blockIdx.x, q = threadIdx.x;
    if (b < 64) {                                // L1: KPAD=32, IN=5
        const int col = b;
        if (q < 16) {
            __half2 v = __halves2half2(__float2half(0.f), __float2half(0.f));
            if (q < 5)
                v = __halves2half2(__float2half(U1[q * 64 + col]),
                                   __float2half(V2a[q * 64 + col]));
            *reinterpret_cast<__half2*>(&BTa[col * 32 + 2 * q]) = v;
        }
    } else if (b < 128) {                        // L2: KPAD=128, IN=64
        const int col = b - 64;
        const __half2 v = __halves2half2(__float2half(U2[q * 64 + col]),
                                         __float2half(V2b[q * 64 + col]));
        *reinterpret_cast<__half2*>(&BTb[col * 128 + 2 * q]) = v;
    } else {                                     // L3
        const int col = b - 128;
        const __half2 v = __halves2half2(__float2half(U3[q * 64 + col]),
                                         __float2half(V2c[q * 64 + col]));
        *reinterpret_cast<__half2*>(&BTc[col * 128 + 2 * q]) = v;
    }
}

// ---------------------------------------------------------------- layer 1 (IN=5)
// R20 packed-fp16 x gather, 2-lane groups; R21: 8-deep load pipeline.
__global__ __launch_bounds__(512, 6) void fused_layer8(
        const __half* __restrict__ x16,
        const unsigned* __restrict__ slots,
        const unsigned* __restrict__ cnt,
        const float* __restrict__ invcnt,
        const __half* __restrict__ BT16,         // [64][32]
        const float* __restrict__ cp,
        __half* __restrict__ hnextH) {
    __shared__ __align__(16) char Ab[256 * 64];  // 16 KB A-tile (K=32 fp16)

    const int tid  = threadIdx.x;
    const int wv   = __builtin_amdgcn_readfirstlane(tid >> 6);
    const int lane = tid & 63;
    const int g = lane >> 1, sub = lane & 1;
    const int nb = blockIdx.x * 256;
    const int r  = wv * 32 + g;
    const int n  = nb + r;
    const bool valid = n < N_NODES;

    const unsigned sent  = (unsigned)N_NODES;    // zeroed sentinel row
    const unsigned selfi = valid ? (unsigned)n : sent;
    const char* xb = reinterpret_cast<const char*>(x16);
    const uint2 hs = *reinterpret_cast<const uint2*>(xb + ((size_t)selfi << 4) + (sub << 3));
    float m[4];
    {
        const __half2* p = reinterpret_cast<const __half2*>(&hs);
        const float2 f0 = __half22float2(p[0]);
        const float2 f1 = __half22float2(p[1]);
        m[0] = f0.x; m[1] = f0.y; m[2] = f1.x; m[3] = f1.y;   // self loop
    }
    int deg = 0;
    if (valid) { deg = (int)cnt[n]; if (deg > SLOTS) deg = SLOTS; }
    int maxd = deg;                              // wave-uniform bound
#pragma unroll
    for (int off = 1; off < 64; off <<= 1)
        maxd = max(maxd, __shfl_xor(maxd, off));
    const unsigned* srow = slots + (size_t)(valid ? n : 0) * SLOTS;

    uint4 sA = make_uint4(sent, sent, sent, sent);
    uint4 sB = make_uint4(sent, sent, sent, sent);
    if (0 < deg) sA = *reinterpret_cast<const uint4*>(srow);
    if (4 < deg) sB = *reinterpret_cast<const uint4*>(srow + 4);
    for (int j = 0; j < maxd; j += 8) {
        uint4 sC = make_uint4(sent, sent, sent, sent);
        uint4 sD = make_uint4(sent, sent, sent, sent);
        if (j + 8  < deg) sC = *reinterpret_cast<const uint4*>(srow + j + 8);
        if (j + 12 < deg) sD = *reinterpret_cast<const uint4*>(srow + j + 12);
        const unsigned i0 = (j + 0 < deg) ? sA.x : sent;
        const unsigned i1 = (j + 1 < deg) ? sA.y : sent;
        const unsigned i2 = (j + 2 < deg) ? sA.z : sent;
        const unsigned i3 = (j + 3 < deg) ? sA.w : sent;
        const unsigned i4 = (j + 4 < deg) ? sB.x : sent;
        const unsigned i5 = (j + 5 < deg) ? sB.y : sent;
        const unsigned i6 = (j + 6 < deg) ? sB.z : sent;
        const unsigned i7 = (j + 7 < deg) ? sB.w : sent;
        const uint2 v0 = *reinterpret_cast<const uint2*>(xb + ((size_t)i0 << 4) + (sub << 3));
        const uint2 v1 = *reinterpret_cast<const uint2*>(xb + ((size_t)i1 << 4) + (sub << 3));
        const uint2 v2 = *reinterpret_cast<const uint2*>(xb + ((size_t)i2 << 4) + (sub << 3));
        const uint2 v3 = *reinterpret_cast<const uint2*>(xb + ((size_t)i3 << 4) + (sub << 3));
        const uint2 v4 = *reinterpret_cast<const uint2*>(xb + ((size_t)i4 << 4) + (sub << 3));
        const uint2 v5 = *reinterpret_cast<const uint2*>(xb + ((size_t)i5 << 4) + (sub << 3));
        const uint2 v6 = *reinterpret_cast<const uint2*>(xb + ((size_t)i6 << 4) + (sub << 3));
        const uint2 v7 = *reinterpret_cast<const uint2*>(xb + ((size_t)i7 << 4) + (sub << 3));
        accum4(m, v0); accum4(m, v1); accum4(m, v2); accum4(m, v3);
        accum4(m, v4); accum4(m, v5); accum4(m, v6); accum4(m, v7);
        sA = sC; sB = sD;
    }
    const float ic = valid ? invcnt[n] : 0.f;
#pragma unroll
    for (int t = 0; t < 4; ++t) m[t] *= ic;

    // stage A row: halves k=2q -> hp_q, k=2q+1 -> m_q; k>=16 zeroed.
    {
        const unsigned* hw = reinterpret_cast<const unsigned*>(&hs);
        unsigned o[4];
#pragma unroll
        for (int t = 0; t < 2; ++t) {
            const __half2 mh = __float22half2_rn(make_float2(m[2 * t], m[2 * t + 1]));
            const unsigned mw = *reinterpret_cast<const unsigned*>(&mh);
            const unsigned hpw = hw[t];
            o[2 * t]     = (hpw & 0xFFFFu) | (mw << 16);
            o[2 * t + 1] = (hpw >> 16)     | (mw & 0xFFFF0000u);
        }
        const int swz = (r & 3) << 4;
        *reinterpret_cast<uint4*>(&Ab[r * 64 + ((sub * 16) ^ swz)]) =
            make_uint4(o[0], o[1], o[2], o[3]);
        *reinterpret_cast<uint4*>(&Ab[r * 64 + (((2 + sub) * 16) ^ swz)]) =
            make_uint4(0u, 0u, 0u, 0u);
    }

    // B-fragment from BT16 (one dwordx4 per thread)
    const int nt = wv & 3, mtb = wv >> 2;
    const int col = nt * 16 + (lane & 15);
    const half8_t bfrag = *reinterpret_cast<const half8_t*>(&BT16[col * 32 + ((lane >> 4) * 8)]);
    const float cpl = cp[col];
    __syncthreads();

    // MFMA: 8 tiles per wave (mt = mtb + 2t)
    const int rq = lane & 15, q4 = lane >> 4;
    f32x4_t acc[8];
#pragma unroll
    for (int t = 0; t < 8; ++t) {
        const int row = (mtb + 2 * t) * 16 + rq;
        const int cb  = (q4 * 16) ^ ((row & 3) << 4);
        const half8_t af = *reinterpret_cast<const half8_t*>(&Ab[row * 64 + cb]);
        f32x4_t z = {0.f, 0.f, 0.f, 0.f};
        acc[t] = __builtin_amdgcn_mfma_f32_16x16x32_f16(af, bfrag, z, 0, 0, 0);
    }
#pragma unroll
    for (int t = 0; t < 8; ++t) {
#pragma unroll
        for (int rr = 0; rr < 4; ++rr) {
            const int row  = (mtb + 2 * t) * 16 + q4 * 4 + rr;
            const int node = nb + row;
            if (node < N_NODES)
                hnextH[(size_t)node * 64 + col] =
                    __float2half(fmaxf(acc[t][rr] + cpl, 0.f));
        }
    }
}

// ---------------------------------------------------------------- layers 2/3 (IN=64)
// R18 packed gather + R20 BT16 + R21 8-deep load pipeline (MLP doubling:
// the gather was outstanding-request-limited at 4 loads/wave in flight).
template <bool OUT16, bool HEADS>
__global__ __launch_bounds__(512, 6) void fused_layer64(
        const __half* __restrict__ hprevH,
        const unsigned* __restrict__ slots,
        const unsigned* __restrict__ cnt,
        const float* __restrict__ invcnt,
        const __half* __restrict__ BT16,         // [64][128]
        const float* __restrict__ cp,
        float* __restrict__ hnextF,
        __half* __restrict__ hnextH,
        const float* __restrict__ bs,  const float* __restrict__ bst,
        const float* __restrict__ bo,
        const float* __restrict__ Ws,  const float* __restrict__ Wst,
        const float* __restrict__ Wo,
        float* __restrict__ state, float* __restrict__ part) {
    __shared__ __align__(16) char Ab[64 * 256];          // 16 KB A-tile
    __shared__ float Hh[HEADS ? 64 * 64 : 8];            // 16 KB h stage (L3)
    __shared__ float Wl[HEADS ? 256 : 8];                // head weights f-major
    __shared__ float sgl[HEADS ? 64 : 8];
    __shared__ float ocl[HEADS ? 64 : 8];

    const int tid  = threadIdx.x;
    const int wv   = __builtin_amdgcn_readfirstlane(tid >> 6);
    const int lane = tid & 63;
    const int g = lane >> 3, sub = lane & 7;
    const int nb = blockIdx.x * 64;
    const int r  = wv * 8 + g;                           // block-local A row
    const int n  = nb + r;
    const bool valid = n < N_NODES;

    if constexpr (HEADS) {
        if (tid < 256) {
            const int f = tid >> 2, c = tid & 3;
            float w;
            if      (c == 0) w = Ws[f * 2];
            else if (c == 1) w = Ws[f * 2 + 1];
            else if (c == 2) w = Wst[f];
            else             w = Wo[f];
            Wl[tid] = w;
        }
    }

    // ---- packed gather-mean, 8-deep
    const unsigned sent  = (unsigned)N_NODES;            // zeroed sentinel row
    const unsigned selfi = valid ? (unsigned)n : sent;
    const char* hb = reinterpret_cast<const char*>(hprevH);
    const uint4 hs = *reinterpret_cast<const uint4*>(hb + ((size_t)selfi << 7) + (sub << 4));
    float m[8];
    {
        const __half2* p = reinterpret_cast<const __half2*>(&hs);
#pragma unroll
        for (int t = 0; t < 4; ++t) {
            const float2 f = __half22float2(p[t]);
            m[2 * t] = f.x; m[2 * t + 1] = f.y;          // self loop
        }
    }
    int deg = 0;
    if (valid) { deg = (int)cnt[n]; if (deg > SLOTS) deg = SLOTS; }
    int maxd = deg;                                      // wave-uniform bound
#pragma unroll
    for (int off = 8; off < 64; off <<= 1)
        maxd = max(maxd, __shfl_xor(maxd, off));
    const unsigned* srow = slots + (size_t)(valid ? n : 0) * SLOTS;

    uint4 sA = make_uint4(sent, sent, sent, sent);
    uint4 sB = make_uint4(sent, sent, sent, sent);
    if (0 < deg) sA = *reinterpret_cast<const uint4*>(srow);
    if (4 < deg) sB = *reinterpret_cast<const uint4*>(srow + 4);
    for (int j = 0; j < maxd; j += 8) {
        uint4 sC = make_uint4(sent, sent, sent, sent);
        uint4 sD = make_uint4(sent, sent, sent, sent);
        if (j + 8  < deg) sC = *reinterpret_cast<const uint4*>(srow + j + 8);
        if (j + 12 < deg) sD = *reinterpret_cast<const uint4*>(srow + j + 12);
        const unsigned i0 = (j + 0 < deg) ? sA.x : sent;
        const unsigned i1 = (j + 1 < deg) ? sA.y : sent;
        const unsigned i2 = (j + 2 < deg) ? sA.z : sent;
        const unsigned i3 = (j + 3 < deg) ? sA.w : sent;
        const unsigned i4 = (j + 4 < deg) ? sB.x : sent;
        const unsigned i5 = (j + 5 < deg) ? sB.y : sent;
        const unsigned i6 = (j + 6 < deg) ? sB.z : sent;
        const unsigned i7 = (j + 7 < deg) ? sB.w : sent;
        const uint4 v0 = *reinterpret_cast<const uint4*>(hb + ((size_t)i0 << 7) + (sub << 4));
        const uint4 v1 = *reinterpret_cast<const uint4*>(hb + ((size_t)i1 << 7) + (sub << 4));
        const uint4 v2 = *reinterpret_cast<const uint4*>(hb + ((size_t)i2 << 7) + (sub << 4));
        const uint4 v3 = *reinterpret_cast<const uint4*>(hb + ((size_t)i3 << 7) + (sub << 4));
        const uint4 v4 = *reinterpret_cast<const uint4*>(hb + ((size_t)i4 << 7) + (sub << 4));
        const uint4 v5 = *reinterpret_cast<const uint4*>(hb + ((size_t)i5 << 7) + (sub << 4));
        const uint4 v6 = *reinterpret_cast<const uint4*>(hb + ((size_t)i6 << 7) + (sub << 4));
        const uint4 v7 = *reinterpret_cast<const uint4*>(hb + ((size_t)i7 << 7) + (sub << 4));
        accum8(m, v0); accum8(m, v1); accum8(m, v2); accum8(m, v3);
        accum8(m, v4); accum8(m, v5); accum8(m, v6); accum8(m, v7);
        sA = sC; sB = sD;
    }
    const float ic = valid ? invcnt[n] : 0.f;
#pragma unroll
    for (int t = 0; t < 8; ++t) m[t] *= ic;

    // interleave (hp, m) -> fp16 pairs, 2 swizzled b128 writes
    {
        unsigned out[8];
        const unsigned* hw = reinterpret_cast<const unsigned*>(&hs);
#pragma unroll
        for (int t = 0; t < 4; ++t) {
            const __half2 mh = __float22half2_rn(make_float2(m[2 * t], m[2 * t + 1]));
            const unsigned mw = *reinterpret_cast<const unsigned*>(&mh);
            const unsigned hpw = hw[t];
            out[2 * t]     = (hpw & 0xFFFFu) | (mw << 16);
            out[2 * t + 1] = (hpw >> 16)     | (mw & 0xFFFF0000u);
        }
        const int swz = (r & 7) << 4;
        uint4 lo = make_uint4(out[0], out[1], out[2], out[3]);
        uint4 hi = make_uint4(out[4], out[5], out[6], out[7]);
        *reinterpret_cast<uint4*>(&Ab[r * 256 + ((sub * 32)      ^ swz)]) = lo;
        *reinterpret_cast<uint4*>(&Ab[r * 256 + ((sub * 32 + 16) ^ swz)]) = hi;
    }

    // ---- B-fragments from BT16 (4 dwordx4 per thread; pre-barrier)
    const int nt = wv & 3, mt0 = wv >> 2;                // tiles (mt0,nt) and (mt0+2,nt)
    const int col = nt * 16 + (lane & 15);
    half8_t bfrag[4];
#pragma unroll
    for (int kt = 0; kt < 4; ++kt)
        bfrag[kt] = *reinterpret_cast<const half8_t*>(
            &BT16[col * 128 + kt * 32 + ((lane >> 4) * 8)]);
    const float cpl = cp[col];
    __syncthreads();

    // ---- MFMA phase: 2 tiles per wave, shared bfrag
    f32x4_t acc0 = {0.f, 0.f, 0.f, 0.f};
    f32x4_t acc1 = {0.f, 0.f, 0.f, 0.f};
    const int rq = lane & 15, q16 = (lane >> 4) * 16;
#pragma unroll
    for (int kt = 0; kt < 4; ++kt) {
        const int row0 = mt0 * 16 + rq;
        const int row1 = row0 + 32;
        const int cb   = kt * 64 + q16;
        const int swz  = (row0 & 7) << 4;                // row1&7 == row0&7
        const half8_t a0 = *reinterpret_cast<const half8_t*>(&Ab[row0 * 256 + (cb ^ swz)]);
        const half8_t a1 = *reinterpret_cast<const half8_t*>(&Ab[row1 * 256 + (cb ^ swz)]);
        acc0 = __builtin_amdgcn_mfma_f32_16x16x32_f16(a0, bfrag[kt], acc0, 0, 0, 0);
        acc1 = __builtin_amdgcn_mfma_f32_16x16x32_f16(a1, bfrag[kt], acc1, 0, 0, 0);
    }

    // ---- epilogue: bias + relu + store
#pragma unroll
    for (int t = 0; t < 4; ++t) {
        const int row  = mt0 * 16 + ((lane >> 4) * 4) + t;
        const int node = nb + row;
        const float h  = fmaxf(acc0[t] + cpl, 0.f);
        if (node < N_NODES) {
            if constexpr (OUT16) hnextH[(size_t)node * 64 + col] = __float2half(h);
            else                 hnextF[(size_t)node * 64 + col] = h;
        }
        if constexpr (HEADS) Hh[row * 64 + col] = h;
    }
#pragma unroll
    for (int t = 0; t < 4; ++t) {
        const int row  = (mt0 + 2) * 16 + ((lane >> 4) * 4) + t;
        const int node = nb + row;
        const float h  = fmaxf(acc1[t] + cpl, 0.f);
        if (node < N_NODES) {
            if constexpr (OUT16) hnextH[(size_t)node * 64 + col] = __float2half(h);
            else                 hnextF[(size_t)node * 64 + col] = h;
        }
        if constexpr (HEADS) Hh[row * 64 + col] = h;
    }

    // ---- fused heads (layer 3): 8 threads per node
    if constexpr (HEADS) {
        __syncthreads();
        const int nl = tid >> 3, sb2 = tid & 7;
        const float4 h0 = *reinterpret_cast<const float4*>(&Hh[nl * 64 + sb2 * 8]);
        const float4 h1 = *reinterpret_cast<const float4*>(&Hh[nl * 64 + sb2 * 8 + 4]);
        float r0 = 0.f, r1 = 0.f, r2 = 0.f, r3 = 0.f;
        const float hv[8] = {h0.x, h0.y, h0.z, h0.w, h1.x, h1.y, h1.z, h1.w};
#pragma unroll
        for (int t = 0; t < 8; ++t) {
            const float4 w = *reinterpret_cast<const float4*>(&Wl[(sb2 * 8 + t) * 4]);
            r0 += hv[t] * w.x; r1 += hv[t] * w.y; r2 += hv[t] * w.z; r3 += hv[t] * w.w;
        }
#pragma unroll
        for (int off = 1; off < 8; off <<= 1) {
            r0 += __shfl_xor(r0, off); r1 += __shfl_xor(r1, off);
            r2 += __shfl_xor(r2, off); r3 += __shfl_xor(r3, off);
        }
        if (sb2 == 0) {
            const int node = nb + nl;
            float sg = 0.f, oc = 0.f;
            if (node < N_NODES) {
                state[(size_t)node * 2 + 0] = r0 + bs[0];
                state[(size_t)node * 2 + 1] = r1 + bs[1];
                sg = 1.0f / (1.0f + __expf(-(r2 + bst[0])));
                oc = r3 + bo[0];
            }
            sgl[nl] = sg; ocl[nl] = oc;
        }
        __syncthreads();
        if (tid < 64) {
            float a = sgl[tid], b = ocl[tid];
#pragma unroll
            for (int off = 1; off < 64; off <<= 1) {
                a += __shfl_xor(a, off); b += __shfl_xor(b, off);
            }
            if (tid == 0) {
                part[blockIdx.x * 2 + 0] = a;
                part[blockIdx.x * 2 + 1] = b;
            }
        }
    }
}

// ---------------------------------------------------------------- final reduce

__global__ __launch_bounds__(1024) void final_reduce(const float* __restrict__ part,
                                                     float* __restrict__ scal) {
    __shared__ float l0[1024], l1[1024];
    const int t = threadIdx.x;
    float a = 0.f, b = 0.f;
    for (int i = t; i < HEAD_BLOCKS; i += 1024) { a += part[2 * i]; b += part[2 * i + 1]; }
    l0[t] = a; l1[t] = b;
    __syncthreads();
    for (int off = 512; off; off >>= 1) {
        if (t < off) { l0[t] += l0[t + off]; l1[t] += l1[t + off]; }
        __syncthreads();
    }
    if (t == 0) {
        scal[0] = l0[0] / (float)N_NODES;   // stability
        scal[1] = l1[0] / (float)N_NODES;   // opf_cost
    }
}

// ---------------------------------------------------------------- launch

extern "C" void kernel_launch(void* const* d_in, const int* in_sizes, int n_in,
                              void* d_out, int out_size, void* d_ws, size_t ws_size,
                              hipStream_t stream) {
    const float* x   = (const float*)d_in[0];
    const int*   ei  = (const int*)d_in[1];
    const float* W1  = (const float*)d_in[2];
    const float* b1  = (const float*)d_in[3];
    const float* U1  = (const float*)d_in[4];
    const float* c1  = (const float*)d_in[5];
    const float* W2  = (const float*)d_in[6];
    const float* b2  = (const float*)d_in[7];
    const float* U2  = (const float*)d_in[8];
    const float* c2  = (const float*)d_in[9];
    const float* W3  = (const float*)d_in[10];
    const float* b3  = (const float*)d_in[11];
    const float* U3  = (const float*)d_in[12];
    const float* c3  = (const float*)d_in[13];
    const float* Ws  = (const float*)d_in[14];
    const float* bs  = (const float*)d_in[15];
    const float* Wst = (const float*)d_in[16];
    const float* bst = (const float*)d_in[17];
    const float* Wo  = (const float*)d_in[18];
    const float* bo  = (const float*)d_in[19];

    const int* src = ei;              // edge_index[0]
    const int* dst = ei + N_EDGES;    // edge_index[1]

    char* wsp = (char*)d_ws;
    size_t off = 0;
    auto alloc = [&](size_t bytes) -> char* {
        char* p = wsp + off;
        off = (off + bytes + 255) & ~(size_t)255;
        return p;
    };
    unsigned* cnt    = (unsigned*)alloc((size_t)N_NODES * 4);
    float*    invcnt = (float*)   alloc((size_t)N_NODES * 4);
    float*    part   = (float*)   alloc((size_t)HEAD_BLOCKS * 2 * 4);
    unsigned* cursor = (unsigned*)alloc((size_t)NBUCK * 4);
    float*    V2a    = (float*)   alloc((size_t)5 * 64 * 4);
    float*    V2b    = (float*)   alloc((size_t)64 * 64 * 4);
    float*    V2c    = (float*)   alloc((size_t)64 * 64 * 4);
    float*    cpa    = (float*)   alloc((size_t)64 * 4);
    float*    cpb    = (float*)   alloc((size_t)64 * 4);
    float*    cpc    = (float*)   alloc((size_t)64 * 4);
    __half*   BTa    = (__half*)  alloc((size_t)64 * 32 * 2);
    __half*   BTb    = (__half*)  alloc((size_t)64 * 128 * 2);
    __half*   BTc    = (__half*)  alloc((size_t)64 * 128 * 2);
    __half*   x16    = (__half*)  alloc(((size_t)N_NODES + 1) * 8 * 2);   // padded x + sentinel
    unsigned* slots  = (unsigned*)alloc((size_t)N_NODES * SLOTS * 4);     // 19.2 MB
    __half*   h16A   = (__half*)  alloc(((size_t)N_NODES + 1) * 64 * 2);  // +sentinel row
    __half*   h16B   = (__half*)  alloc(((size_t)N_NODES + 1) * 64 * 2);
    // packed edge buckets (5.6 MB) alias h16B: dead until layer-2 writes h16B.
    unsigned* packed = (unsigned*)h16B;

    float* out   = (float*)d_out;
    float* state = out;                 // [N, 2]
    float* scal  = out + 200000;        // stability, opf_cost
    float* hout  = out + 200002;        // [N, 64]

    const int PB = (N_EDGES + CHUNK - 1) / CHUNK;   // 293

    // weight folding (graph-independent)
    precompute_v<5> <<<2, 256, 0, stream>>>(W1, b1, U1, c1, V2a, cpa);
    precompute_v<64><<<17, 256, 0, stream>>>(W2, b2, U2, c2, V2b, cpb);
    precompute_v<64><<<17, 256, 0, stream>>>(W3, b3, U3, c3, V2c, cpc);
    bt_build<<<192, 64, 0, stream>>>(U1, V2a, U2, V2b, U3, V2c, BTa, BTb, BTc);

    // x16 convert + cursor/sentinel init, then bucketed adjacency build
    convert_init<<<L1_BLOCKS, 256, 0, stream>>>(x, x16, cursor, h16A, h16B);
    edge_partition<<<PB, 256, 0, stream>>>(src, dst, cursor, packed);
    bucket_build<<<NBUCK, 256, 0, stream>>>(packed, cursor, slots, cnt, invcnt);

    // L1: packed fp16 x gather (256-node blocks)
    fused_layer8<<<L1_BLOCKS, 512, 0, stream>>>(
        x16, slots, cnt, invcnt, BTa, cpa, h16A);
    // L2/L3: packed-gather 64-node blocks
    fused_layer64<true, false><<<HEAD_BLOCKS, 512, 0, stream>>>(
        h16A, slots, cnt, invcnt, BTb, cpb, nullptr, h16B,
        nullptr, nullptr, nullptr, nullptr, nullptr, nullptr, nullptr, nullptr);
    fused_layer64<false, true><<<HEAD_BLOCKS, 512, 0, stream>>>(
        h16B, slots, cnt, invcnt, BTc, cpc, hout, nullptr,
        bs, bst, bo, Ws, Wst, Wo, state, part);
    final_reduce<<<1, 1024, 0, stream>>>(part, scal);
}

// Round 9
// 243.121 us; speedup vs baseline: 1.2327x; 1.2327x over previous
//
#include <hip/hip_runtime.h>
#include <hip/hip_fp16.h>
#include <math.h>

#define N_NODES 100000
#define N_EDGES 1200000
#define SLOTS   48                              // Poisson(12): P(any deg>48) ~ 3e-10
#define HEAD_BLOCKS ((N_NODES + 63) / 64)       // L2/L3 grid: 1563 blocks, 64 nodes
#define L1_BLOCKS  ((N_NODES + 255) / 256)      // L1 grid: 391 blocks, 256 nodes

// bucketed adjacency build (R19)
#define BNODES 256                              // nodes per bucket (dst>>8)
#define NBUCK  ((N_NODES + BNODES - 1) / BNODES)   // 391
#define BCAP   3584                             // 9.3 sigma above mean 3070
#define CHUNK  4096                             // edges per partition block

typedef _Float16 half8_t __attribute__((ext_vector_type(8)));
typedef float    f32x4_t __attribute__((ext_vector_type(4)));

// ---------------------------------------------------------------- utilities

__device__ __forceinline__ float bcastf(float v, int l) {
    return __uint_as_float(__builtin_amdgcn_readlane(__float_as_uint(v), (unsigned)l));
}

__device__ __forceinline__ void accum8(float* m, const uint4& v) {
    const __half2* p = reinterpret_cast<const __half2*>(&v);
#pragma unroll
    for (int t = 0; t < 4; ++t) {
        const float2 f = __half22float2(p[t]);
        m[2 * t] += f.x; m[2 * t + 1] += f.y;
    }
}

__device__ __forceinline__ void accum4(float* m, const uint2& v) {
    const __half2* p = reinterpret_cast<const __half2*>(&v);
    const float2 f0 = __half22float2(p[0]);
    const float2 f1 = __half22float2(p[1]);
    m[0] += f0.x; m[1] += f0.y; m[2] += f1.x; m[3] += f1.y;
}

// x -> padded fp16 [N+1][8]; + cursor zero + h-buffer sentinel rows zero
__global__ __launch_bounds__(256) void convert_init(const float* __restrict__ x,
                                                    __half* __restrict__ x16,
                                                    unsigned* __restrict__ cursor,
                                                    __half* __restrict__ zA,
                                                    __half* __restrict__ zB) {
    const int gid = blockIdx.x * 256 + threadIdx.x;
    if (gid <= N_NODES) {
        __half h[8];
#pragma unroll
        for (int i = 0; i < 8; ++i) h[i] = __float2half(0.f);
        if (gid < N_NODES) {
#pragma unroll
            for (int i = 0; i < 5; ++i) h[i] = __float2half(x[gid * 5 + i]);
        }
        *reinterpret_cast<uint4*>(&x16[(size_t)gid * 8]) =
            *reinterpret_cast<const uint4*>(h);
    }
    if (gid < NBUCK) cursor[gid] = 0u;
    if (gid < 64) {
        zA[(size_t)N_NODES * 64 + gid] = __float2half(0.f);
        zB[(size_t)N_NODES * 64 + gid] = __float2half(0.f);
    }
}

// ---------------------------------------------------------------- adjacency build
// Pass 1: partition edges into dst-range buckets (LDS histogram -> one cursor
// reservation per (block,bucket) -> run appends). R19-proven.
__global__ __launch_bounds__(256) void edge_partition(const int* __restrict__ src,
                                                      const int* __restrict__ dst,
                                                      unsigned* __restrict__ cursor,
                                                      unsigned* __restrict__ packed) {
    __shared__ unsigned histL[NBUCK];
    __shared__ unsigned baseL[NBUCK];
    const int tid = threadIdx.x;
    const int e0 = blockIdx.x * CHUNK;
    for (int b = tid; b < NBUCK; b += 256) histL[b] = 0u;
    __syncthreads();
#pragma unroll
    for (int i = 0; i < CHUNK / 256; ++i) {
        const int e = e0 + i * 256 + tid;
        if (e < N_EDGES) atomicAdd(&histL[(unsigned)dst[e] >> 8], 1u);
    }
    __syncthreads();
    for (int b = tid; b < NBUCK; b += 256) {
        const unsigned c = histL[b];
        baseL[b] = c ? atomicAdd(&cursor[b], c) : 0u;
        histL[b] = 0u;                           // reuse as local position counter
    }
    __syncthreads();
#pragma unroll
    for (int i = 0; i < CHUNK / 256; ++i) {
        const int e = e0 + i * 256 + tid;
        if (e < N_EDGES) {
            const unsigned d = (unsigned)dst[e], s = (unsigned)src[e];
            const unsigned b = d >> 8;
            const unsigned r = atomicAdd(&histL[b], 1u);
            const unsigned pos = baseL[b] + r;
            if (pos < BCAP)                       // astronomically-rare overflow guard
                packed[(size_t)b * BCAP + pos] = ((d & 255u) << 17) | s;
        }
    }
}

// Pass 2: one block per bucket; slot rows built in LDS, streamed out coalesced.
__global__ __launch_bounds__(256) void bucket_build(const unsigned* __restrict__ packed,
                                                    const unsigned* __restrict__ cursor,
                                                    unsigned* __restrict__ slots,
                                                    unsigned* __restrict__ cnt,
                                                    float* __restrict__ invcnt) {
    __shared__ __align__(16) unsigned slotsL[BNODES * SLOTS];   // 48 KB
    __shared__ unsigned cntL[BNODES];
    const int tid = threadIdx.x;
    const int b = blockIdx.x;
    cntL[tid] = 0u;
    __syncthreads();
    const unsigned nE = min(cursor[b], (unsigned)BCAP);
    const unsigned* pb = packed + (size_t)b * BCAP;
    for (unsigned i = tid; i < nE; i += 256) {
        const unsigned p = pb[i];
        const unsigned dl = p >> 17;
        const unsigned r = atomicAdd(&cntL[dl], 1u);
        if (r < SLOTS) slotsL[dl * SLOTS + r] = p & 0x1FFFFu;
    }
    __syncthreads();
    const int nvalid = min(N_NODES - b * BNODES, BNODES);
    const uint4* sl4 = reinterpret_cast<const uint4*>(slotsL);
    uint4* sg4 = reinterpret_cast<uint4*>(slots) + (size_t)b * (BNODES * SLOTS / 4);
    const int l4 = nvalid * (SLOTS / 4);
    for (int i = tid; i < l4; i += 256) sg4[i] = sl4[i];
    if (tid < nvalid) {
        const int node = b * BNODES + tid;
        const unsigned c = cntL[tid];
        cnt[node] = c;
        invcnt[node] = 1.0f / (float)(c + 1u);   // +1 self loop
    }
}

// ---------------------------------------------------------------- weight folding
// V2 = W @ U_bot [IN,64];  cp = c + b @ U_bot [64]
template <int IN>
__global__ __launch_bounds__(256) void precompute_v(const float* __restrict__ W,
                                                    const float* __restrict__ b,
                                                    const float* __restrict__ U,
                                                    const float* __restrict__ c,
                                                    float* __restrict__ V2,
                                                    float* __restrict__ cp) {
    __shared__ float Ub[64 * 64];
    const int tid = threadIdx.x;
    for (int j = tid; j < 64 * 64; j += 256) Ub[j] = U[IN * 64 + j];
    __syncthreads();
    const int w = tid >> 6, lane = tid & 63;
    const int r = blockIdx.x * 4 + w;
    if (r > IN) return;
    const float wv = (r < IN) ? W[r * 64 + lane] : b[lane];
    float o = (r < IN) ? 0.f : c[lane];
#pragma unroll 8
    for (int k = 0; k < 64; ++k) o += bcastf(wv, k) * Ub[k * 64 + lane];
    if (r < IN) V2[r * 64 + lane] = o;
    else        cp[lane] = o;
}

// Interleaved-transposed fp16 weights: BT[col][k], k=2q -> Utop[q][col],
// k=2q+1 -> V2[q][col].
__global__ __launch_bounds__(64) void bt_build(const float* __restrict__ U1,
                                               const float* __restrict__ V2a,
                                               const float* __restrict__ U2,
                                               const float* __restrict__ V2b,
                                               const float* __restrict__ U3,
                                               const float* __restrict__ V2c,
                                               __half* __restrict__ BTa,
                                               __half* __restrict__ BTb,
                                               __half* __restrict__ BTc) {
    const int b = blockIdx.x, q = threadIdx.x;
    if (b < 64) {                                // L1: KPAD=32, IN=5
        const int col = b;
        if (q < 16) {
            __half2 v = __halves2half2(__float2half(0.f), __float2half(0.f));
            if (q < 5)
                v = __halves2half2(__float2half(U1[q * 64 + col]),
                                   __float2half(V2a[q * 64 + col]));
            *reinterpret_cast<__half2*>(&BTa[col * 32 + 2 * q]) = v;
        }
    } else if (b < 128) {                        // L2: KPAD=128, IN=64
        const int col = b - 64;
        const __half2 v = __halves2half2(__float2half(U2[q * 64 + col]),
                                         __float2half(V2b[q * 64 + col]));
        *reinterpret_cast<__half2*>(&BTb[col * 128 + 2 * q]) = v;
    } else {                                     // L3
        const int col = b - 128;
        const __half2 v = __halves2half2(__float2half(U3[q * 64 + col]),
                                         __float2half(V2c[q * 64 + col]));
        *reinterpret_cast<__half2*>(&BTc[col * 128 + 2 * q]) = v;
    }
}

// ---------------------------------------------------------------- layer 1 (IN=5)
// R20 packed-fp16 x gather, 2-lane groups, 4-deep (proven; x16 is L2-resident
// so latency is short -- deep pipelining unnecessary here).
__global__ __launch_bounds__(512, 6) void fused_layer8(
        const __half* __restrict__ x16,
        const unsigned* __restrict__ slots,
        const unsigned* __restrict__ cnt,
        const float* __restrict__ invcnt,
        const __half* __restrict__ BT16,         // [64][32]
        const float* __restrict__ cp,
        __half* __restrict__ hnextH) {
    __shared__ __align__(16) char Ab[256 * 64];  // 16 KB A-tile (K=32 fp16)

    const int tid  = threadIdx.x;
    const int wv   = __builtin_amdgcn_readfirstlane(tid >> 6);
    const int lane = tid & 63;
    const int g = lane >> 1, sub = lane & 1;
    const int nb = blockIdx.x * 256;
    const int r  = wv * 32 + g;
    const int n  = nb + r;
    const bool valid = n < N_NODES;

    const unsigned sent  = (unsigned)N_NODES;    // zeroed sentinel row
    const unsigned selfi = valid ? (unsigned)n : sent;
    const char* xb = reinterpret_cast<const char*>(x16);
    const uint2 hs = *reinterpret_cast<const uint2*>(xb + ((size_t)selfi << 4) + (sub << 3));
    float m[4];
    {
        const __half2* p = reinterpret_cast<const __half2*>(&hs);
        const float2 f0 = __half22float2(p[0]);
        const float2 f1 = __half22float2(p[1]);
        m[0] = f0.x; m[1] = f0.y; m[2] = f1.x; m[3] = f1.y;   // self loop
    }
    int deg = 0;
    if (valid) { deg = (int)cnt[n]; if (deg > SLOTS) deg = SLOTS; }
    int maxd = deg;                              // wave-uniform bound
#pragma unroll
    for (int off = 1; off < 64; off <<= 1)
        maxd = max(maxd, __shfl_xor(maxd, off));
    const unsigned* srow = slots + (size_t)(valid ? n : 0) * SLOTS;

    uint4 s4 = make_uint4(sent, sent, sent, sent);
    if (0 < deg) s4 = *reinterpret_cast<const uint4*>(srow);
    for (int j = 0; j < maxd; j += 4) {
        uint4 s4n = make_uint4(sent, sent, sent, sent);
        if (j + 4 < deg) s4n = *reinterpret_cast<const uint4*>(srow + j + 4);
        const unsigned i0 = (j + 0 < deg) ? s4.x : sent;
        const unsigned i1 = (j + 1 < deg) ? s4.y : sent;
        const unsigned i2 = (j + 2 < deg) ? s4.z : sent;
        const unsigned i3 = (j + 3 < deg) ? s4.w : sent;
        const uint2 v0 = *reinterpret_cast<const uint2*>(xb + ((size_t)i0 << 4) + (sub << 3));
        const uint2 v1 = *reinterpret_cast<const uint2*>(xb + ((size_t)i1 << 4) + (sub << 3));
        const uint2 v2 = *reinterpret_cast<const uint2*>(xb + ((size_t)i2 << 4) + (sub << 3));
        const uint2 v3 = *reinterpret_cast<const uint2*>(xb + ((size_t)i3 << 4) + (sub << 3));
        accum4(m, v0); accum4(m, v1); accum4(m, v2); accum4(m, v3);
        s4 = s4n;
    }
    const float ic = valid ? invcnt[n] : 0.f;
#pragma unroll
    for (int t = 0; t < 4; ++t) m[t] *= ic;

    // stage A row: halves k=2q -> hp_q, k=2q+1 -> m_q; k>=16 zeroed.
    {
        const unsigned* hw = reinterpret_cast<const unsigned*>(&hs);
        unsigned o[4];
#pragma unroll
        for (int t = 0; t < 2; ++t) {
            const __half2 mh = __float22half2_rn(make_float2(m[2 * t], m[2 * t + 1]));
            const unsigned mw = *reinterpret_cast<const unsigned*>(&mh);
            const unsigned hpw = hw[t];
            o[2 * t]     = (hpw & 0xFFFFu) | (mw << 16);
            o[2 * t + 1] = (hpw >> 16)     | (mw & 0xFFFF0000u);
        }
        const int swz = (r & 3) << 4;
        *reinterpret_cast<uint4*>(&Ab[r * 64 + ((sub * 16) ^ swz)]) =
            make_uint4(o[0], o[1], o[2], o[3]);
        *reinterpret_cast<uint4*>(&Ab[r * 64 + (((2 + sub) * 16) ^ swz)]) =
            make_uint4(0u, 0u, 0u, 0u);
    }

    // B-fragment from BT16 (one dwordx4 per thread)
    const int nt = wv & 3, mtb = wv >> 2;
    const int col = nt * 16 + (lane & 15);
    const half8_t bfrag = *reinterpret_cast<const half8_t*>(&BT16[col * 32 + ((lane >> 4) * 8)]);
    const float cpl = cp[col];
    __syncthreads();

    // MFMA: 8 tiles per wave (mt = mtb + 2t)
    const int rq = lane & 15, q4 = lane >> 4;
    f32x4_t acc[8];
#pragma unroll
    for (int t = 0; t < 8; ++t) {
        const int row = (mtb + 2 * t) * 16 + rq;
        const int cb  = (q4 * 16) ^ ((row & 3) << 4);
        const half8_t af = *reinterpret_cast<const half8_t*>(&Ab[row * 64 + cb]);
        f32x4_t z = {0.f, 0.f, 0.f, 0.f};
        acc[t] = __builtin_amdgcn_mfma_f32_16x16x32_f16(af, bfrag, z, 0, 0, 0);
    }
#pragma unroll
    for (int t = 0; t < 8; ++t) {
#pragma unroll
        for (int rr = 0; rr < 4; ++rr) {
            const int row  = (mtb + 2 * t) * 16 + q4 * 4 + rr;
            const int node = nb + row;
            if (node < N_NODES)
                hnextH[(size_t)node * 64 + col] =
                    __float2half(fmaxf(acc[t][rr] + cpl, 0.f));
        }
    }
}

// ---------------------------------------------------------------- layers 2/3 (IN=64)
// R18 packed gather + R20 BT16 + R22 8-deep pipeline at __launch_bounds__(512,4):
// VGPR budget 128 holds the 8 in-flight uint4 rows WITHOUT spilling (R21's
// (512,6)/85-VGPR attempt spilled: WRITE_SIZE 26->136 MB). Outstanding
// loads/CU: 16 waves x 8 = 128 vs R20's 24 x 4 = 96; spill-free this time.
template <bool OUT16, bool HEADS>
__global__ __launch_bounds__(512, 4) void fused_layer64(
        const __half* __restrict__ hprevH,
        const unsigned* __restrict__ slots,
        const unsigned* __restrict__ cnt,
        const float* __restrict__ invcnt,
        const __half* __restrict__ BT16,         // [64][128]
        const float* __restrict__ cp,
        float* __restrict__ hnextF,
        __half* __restrict__ hnextH,
        const float* __restrict__ bs,  const float* __restrict__ bst,
        const float* __restrict__ bo,
        const float* __restrict__ Ws,  const float* __restrict__ Wst,
        const float* __restrict__ Wo,
        float* __restrict__ state, float* __restrict__ part) {
    __shared__ __align__(16) char Ab[64 * 256];          // 16 KB A-tile
    __shared__ float Hh[HEADS ? 64 * 64 : 8];            // 16 KB h stage (L3)
    __shared__ float Wl[HEADS ? 256 : 8];                // head weights f-major
    __shared__ float sgl[HEADS ? 64 : 8];
    __shared__ float ocl[HEADS ? 64 : 8];

    const int tid  = threadIdx.x;
    const int wv   = __builtin_amdgcn_readfirstlane(tid >> 6);
    const int lane = tid & 63;
    const int g = lane >> 3, sub = lane & 7;
    const int nb = blockIdx.x * 64;
    const int r  = wv * 8 + g;                           // block-local A row
    const int n  = nb + r;
    const bool valid = n < N_NODES;

    if constexpr (HEADS) {
        if (tid < 256) {
            const int f = tid >> 2, c = tid & 3;
            float w;
            if      (c == 0) w = Ws[f * 2];
            else if (c == 1) w = Ws[f * 2 + 1];
            else if (c == 2) w = Wst[f];
            else             w = Wo[f];
            Wl[tid] = w;
        }
    }

    // ---- packed gather-mean, 8-deep
    const unsigned sent  = (unsigned)N_NODES;            // zeroed sentinel row
    const unsigned selfi = valid ? (unsigned)n : sent;
    const char* hb = reinterpret_cast<const char*>(hprevH);
    const uint4 hs = *reinterpret_cast<const uint4*>(hb + ((size_t)selfi << 7) + (sub << 4));
    float m[8];
    {
        const __half2* p = reinterpret_cast<const __half2*>(&hs);
#pragma unroll
        for (int t = 0; t < 4; ++t) {
            const float2 f = __half22float2(p[t]);
            m[2 * t] = f.x; m[2 * t + 1] = f.y;          // self loop
        }
    }
    int deg = 0;
    if (valid) { deg = (int)cnt[n]; if (deg > SLOTS) deg = SLOTS; }
    int maxd = deg;                                      // wave-uniform bound
#pragma unroll
    for (int off = 8; off < 64; off <<= 1)
        maxd = max(maxd, __shfl_xor(maxd, off));
    const unsigned* srow = slots + (size_t)(valid ? n : 0) * SLOTS;

    uint4 sA = make_uint4(sent, sent, sent, sent);
    uint4 sB = make_uint4(sent, sent, sent, sent);
    if (0 < deg) sA = *reinterpret_cast<const uint4*>(srow);
    if (4 < deg) sB = *reinterpret_cast<const uint4*>(srow + 4);
    for (int j = 0; j < maxd; j += 8) {
        uint4 sC = make_uint4(sent, sent, sent, sent);
        uint4 sD = make_uint4(sent, sent, sent, sent);
        if (j + 8  < deg) sC = *reinterpret_cast<const uint4*>(srow + j + 8);
        if (j + 12 < deg) sD = *reinterpret_cast<const uint4*>(srow + j + 12);
        const unsigned i0 = (j + 0 < deg) ? sA.x : sent;
        const unsigned i1 = (j + 1 < deg) ? sA.y : sent;
        const unsigned i2 = (j + 2 < deg) ? sA.z : sent;
        const unsigned i3 = (j + 3 < deg) ? sA.w : sent;
        const unsigned i4 = (j + 4 < deg) ? sB.x : sent;
        const unsigned i5 = (j + 5 < deg) ? sB.y : sent;
        const unsigned i6 = (j + 6 < deg) ? sB.z : sent;
        const unsigned i7 = (j + 7 < deg) ? sB.w : sent;
        const uint4 v0 = *reinterpret_cast<const uint4*>(hb + ((size_t)i0 << 7) + (sub << 4));
        const uint4 v1 = *reinterpret_cast<const uint4*>(hb + ((size_t)i1 << 7) + (sub << 4));
        const uint4 v2 = *reinterpret_cast<const uint4*>(hb + ((size_t)i2 << 7) + (sub << 4));
        const uint4 v3 = *reinterpret_cast<const uint4*>(hb + ((size_t)i3 << 7) + (sub << 4));
        const uint4 v4 = *reinterpret_cast<const uint4*>(hb + ((size_t)i4 << 7) + (sub << 4));
        const uint4 v5 = *reinterpret_cast<const uint4*>(hb + ((size_t)i5 << 7) + (sub << 4));
        const uint4 v6 = *reinterpret_cast<const uint4*>(hb + ((size_t)i6 << 7) + (sub << 4));
        const uint4 v7 = *reinterpret_cast<const uint4*>(hb + ((size_t)i7 << 7) + (sub << 4));
        accum8(m, v0); accum8(m, v1); accum8(m, v2); accum8(m, v3);
        accum8(m, v4); accum8(m, v5); accum8(m, v6); accum8(m, v7);
        sA = sC; sB = sD;
    }
    const float ic = valid ? invcnt[n] : 0.f;
#pragma unroll
    for (int t = 0; t < 8; ++t) m[t] *= ic;

    // interleave (hp, m) -> fp16 pairs, 2 swizzled b128 writes
    {
        unsigned out[8];
        const unsigned* hw = reinterpret_cast<const unsigned*>(&hs);
#pragma unroll
        for (int t = 0; t < 4; ++t) {
            const __half2 mh = __float22half2_rn(make_float2(m[2 * t], m[2 * t + 1]));
            const unsigned mw = *reinterpret_cast<const unsigned*>(&mh);
            const unsigned hpw = hw[t];
            out[2 * t]     = (hpw & 0xFFFFu) | (mw << 16);
            out[2 * t + 1] = (hpw >> 16)     | (mw & 0xFFFF0000u);
        }
        const int swz = (r & 7) << 4;
        uint4 lo = make_uint4(out[0], out[1], out[2], out[3]);
        uint4 hi = make_uint4(out[4], out[5], out[6], out[7]);
        *reinterpret_cast<uint4*>(&Ab[r * 256 + ((sub * 32)      ^ swz)]) = lo;
        *reinterpret_cast<uint4*>(&Ab[r * 256 + ((sub * 32 + 16) ^ swz)]) = hi;
    }

    // ---- B-fragments from BT16 (4 dwordx4 per thread; pre-barrier)
    const int nt = wv & 3, mt0 = wv >> 2;                // tiles (mt0,nt) and (mt0+2,nt)
    const int col = nt * 16 + (lane & 15);
    half8_t bfrag[4];
#pragma unroll
    for (int kt = 0; kt < 4; ++kt)
        bfrag[kt] = *reinterpret_cast<const half8_t*>(
            &BT16[col * 128 + kt * 32 + ((lane >> 4) * 8)]);
    const float cpl = cp[col];
    __syncthreads();

    // ---- MFMA phase: 2 tiles per wave, shared bfrag
    f32x4_t acc0 = {0.f, 0.f, 0.f, 0.f};
    f32x4_t acc1 = {0.f, 0.f, 0.f, 0.f};
    const int rq = lane & 15, q16 = (lane >> 4) * 16;
#pragma unroll
    for (int kt = 0; kt < 4; ++kt) {
        const int row0 = mt0 * 16 + rq;
        const int row1 = row0 + 32;
        const int cb   = kt * 64 + q16;
        const int swz  = (row0 & 7) << 4;                // row1&7 == row0&7
        const half8_t a0 = *reinterpret_cast<const half8_t*>(&Ab[row0 * 256 + (cb ^ swz)]);
        const half8_t a1 = *reinterpret_cast<const half8_t*>(&Ab[row1 * 256 + (cb ^ swz)]);
        acc0 = __builtin_amdgcn_mfma_f32_16x16x32_f16(a0, bfrag[kt], acc0, 0, 0, 0);
        acc1 = __builtin_amdgcn_mfma_f32_16x16x32_f16(a1, bfrag[kt], acc1, 0, 0, 0);
    }

    // ---- epilogue: bias + relu + store
#pragma unroll
    for (int t = 0; t < 4; ++t) {
        const int row  = mt0 * 16 + ((lane >> 4) * 4) + t;
        const int node = nb + row;
        const float h  = fmaxf(acc0[t] + cpl, 0.f);
        if (node < N_NODES) {
            if constexpr (OUT16) hnextH[(size_t)node * 64 + col] = __float2half(h);
            else                 hnextF[(size_t)node * 64 + col] = h;
        }
        if constexpr (HEADS) Hh[row * 64 + col] = h;
    }
#pragma unroll
    for (int t = 0; t < 4; ++t) {
        const int row  = (mt0 + 2) * 16 + ((lane >> 4) * 4) + t;
        const int node = nb + row;
        const float h  = fmaxf(acc1[t] + cpl, 0.f);
        if (node < N_NODES) {
            if constexpr (OUT16) hnextH[(size_t)node * 64 + col] = __float2half(h);
            else                 hnextF[(size_t)node * 64 + col] = h;
        }
        if constexpr (HEADS) Hh[row * 64 + col] = h;
    }

    // ---- fused heads (layer 3): 8 threads per node
    if constexpr (HEADS) {
        __syncthreads();
        const int nl = tid >> 3, sb2 = tid & 7;
        const float4 h0 = *reinterpret_cast<const float4*>(&Hh[nl * 64 + sb2 * 8]);
        const float4 h1 = *reinterpret_cast<const float4*>(&Hh[nl * 64 + sb2 * 8 + 4]);
        float r0 = 0.f, r1 = 0.f, r2 = 0.f, r3 = 0.f;
        const float hv[8] = {h0.x, h0.y, h0.z, h0.w, h1.x, h1.y, h1.z, h1.w};
#pragma unroll
        for (int t = 0; t < 8; ++t) {
            const float4 w = *reinterpret_cast<const float4*>(&Wl[(sb2 * 8 + t) * 4]);
            r0 += hv[t] * w.x; r1 += hv[t] * w.y; r2 += hv[t] * w.z; r3 += hv[t] * w.w;
        }
#pragma unroll
        for (int off = 1; off < 8; off <<= 1) {
            r0 += __shfl_xor(r0, off); r1 += __shfl_xor(r1, off);
            r2 += __shfl_xor(r2, off); r3 += __shfl_xor(r3, off);
        }
        if (sb2 == 0) {
            const int node = nb + nl;
            float sg = 0.f, oc = 0.f;
            if (node < N_NODES) {
                state[(size_t)node * 2 + 0] = r0 + bs[0];
                state[(size_t)node * 2 + 1] = r1 + bs[1];
                sg = 1.0f / (1.0f + __expf(-(r2 + bst[0])));
                oc = r3 + bo[0];
            }
            sgl[nl] = sg; ocl[nl] = oc;
        }
        __syncthreads();
        if (tid < 64) {
            float a = sgl[tid], b = ocl[tid];
#pragma unroll
            for (int off = 1; off < 64; off <<= 1) {
                a += __shfl_xor(a, off); b += __shfl_xor(b, off);
            }
            if (tid == 0) {
                part[blockIdx.x * 2 + 0] = a;
                part[blockIdx.x * 2 + 1] = b;
            }
        }
    }
}

// ---------------------------------------------------------------- final reduce

__global__ __launch_bounds__(1024) void final_reduce(const float* __restrict__ part,
                                                     float* __restrict__ scal) {
    __shared__ float l0[1024], l1[1024];
    const int t = threadIdx.x;
    float a = 0.f, b = 0.f;
    for (int i = t; i < HEAD_BLOCKS; i += 1024) { a += part[2 * i]; b += part[2 * i + 1]; }
    l0[t] = a; l1[t] = b;
    __syncthreads();
    for (int off = 512; off; off >>= 1) {
        if (t < off) { l0[t] += l0[t + off]; l1[t] += l1[t + off]; }
        __syncthreads();
    }
    if (t == 0) {
        scal[0] = l0[0] / (float)N_NODES;   // stability
        scal[1] = l1[0] / (float)N_NODES;   // opf_cost
    }
}

// ---------------------------------------------------------------- launch

extern "C" void kernel_launch(void* const* d_in, const int* in_sizes, int n_in,
                              void* d_out, int out_size, void* d_ws, size_t ws_size,
                              hipStream_t stream) {
    const float* x   = (const float*)d_in[0];
    const int*   ei  = (const int*)d_in[1];
    const float* W1  = (const float*)d_in[2];
    const float* b1  = (const float*)d_in[3];
    const float* U1  = (const float*)d_in[4];
    const float* c1  = (const float*)d_in[5];
    const float* W2  = (const float*)d_in[6];
    const float* b2  = (const float*)d_in[7];
    const float* U2  = (const float*)d_in[8];
    const float* c2  = (const float*)d_in[9];
    const float* W3  = (const float*)d_in[10];
    const float* b3  = (const float*)d_in[11];
    const float* U3  = (const float*)d_in[12];
    const float* c3  = (const float*)d_in[13];
    const float* Ws  = (const float*)d_in[14];
    const float* bs  = (const float*)d_in[15];
    const float* Wst = (const float*)d_in[16];
    const float* bst = (const float*)d_in[17];
    const float* Wo  = (const float*)d_in[18];
    const float* bo  = (const float*)d_in[19];

    const int* src = ei;              // edge_index[0]
    const int* dst = ei + N_EDGES;    // edge_index[1]

    char* wsp = (char*)d_ws;
    size_t off = 0;
    auto alloc = [&](size_t bytes) -> char* {
        char* p = wsp + off;
        off = (off + bytes + 255) & ~(size_t)255;
        return p;
    };
    unsigned* cnt    = (unsigned*)alloc((size_t)N_NODES * 4);
    float*    invcnt = (float*)   alloc((size_t)N_NODES * 4);
    float*    part   = (float*)   alloc((size_t)HEAD_BLOCKS * 2 * 4);
    unsigned* cursor = (unsigned*)alloc((size_t)NBUCK * 4);
    float*    V2a    = (float*)   alloc((size_t)5 * 64 * 4);
    float*    V2b    = (float*)   alloc((size_t)64 * 64 * 4);
    float*    V2c    = (float*)   alloc((size_t)64 * 64 * 4);
    float*    cpa    = (float*)   alloc((size_t)64 * 4);
    float*    cpb    = (float*)   alloc((size_t)64 * 4);
    float*    cpc    = (float*)   alloc((size_t)64 * 4);
    __half*   BTa    = (__half*)  alloc((size_t)64 * 32 * 2);
    __half*   BTb    = (__half*)  alloc((size_t)64 * 128 * 2);
    __half*   BTc    = (__half*)  alloc((size_t)64 * 128 * 2);
    __half*   x16    = (__half*)  alloc(((size_t)N_NODES + 1) * 8 * 2);   // padded x + sentinel
    unsigned* slots  = (unsigned*)alloc((size_t)N_NODES * SLOTS * 4);     // 19.2 MB
    __half*   h16A   = (__half*)  alloc(((size_t)N_NODES + 1) * 64 * 2);  // +sentinel row
    __half*   h16B   = (__half*)  alloc(((size_t)N_NODES + 1) * 64 * 2);
    // packed edge buckets (5.6 MB) alias h16B: dead until layer-2 writes h16B.
    unsigned* packed = (unsigned*)h16B;

    float* out   = (float*)d_out;
    float* state = out;                 // [N, 2]
    float* scal  = out + 200000;        // stability, opf_cost
    float* hout  = out + 200002;        // [N, 64]

    const int PB = (N_EDGES + CHUNK - 1) / CHUNK;   // 293

    // weight folding (graph-independent)
    precompute_v<5> <<<2, 256, 0, stream>>>(W1, b1, U1, c1, V2a, cpa);
    precompute_v<64><<<17, 256, 0, stream>>>(W2, b2, U2, c2, V2b, cpb);
    precompute_v<64><<<17, 256, 0, stream>>>(W3, b3, U3, c3, V2c, cpc);
    bt_build<<<192, 64, 0, stream>>>(U1, V2a, U2, V2b, U3, V2c, BTa, BTb, BTc);

    // x16 convert + cursor/sentinel init, then bucketed adjacency build
    convert_init<<<L1_BLOCKS, 256, 0, stream>>>(x, x16, cursor, h16A, h16B);
    edge_partition<<<PB, 256, 0, stream>>>(src, dst, cursor, packed);
    bucket_build<<<NBUCK, 256, 0, stream>>>(packed, cursor, slots, cnt, invcnt);

    // L1: packed fp16 x gather (256-node blocks)
    fused_layer8<<<L1_BLOCKS, 512, 0, stream>>>(
        x16, slots, cnt, invcnt, BTa, cpa, h16A);
    // L2/L3: packed-gather 64-node blocks
    fused_layer64<true, false><<<HEAD_BLOCKS, 512, 0, stream>>>(
        h16A, slots, cnt, invcnt, BTb, cpb, nullptr, h16B,
        nullptr, nullptr, nullptr, nullptr, nullptr, nullptr, nullptr, nullptr);
    fused_layer64<false, true><<<HEAD_BLOCKS, 512, 0, stream>>>(
        h16B, slots, cnt, invcnt, BTc, cpc, hout, nullptr,
        bs, bst, bo, Ws, Wst, Wo, state, part);
    final_reduce<<<1, 1024, 0, stream>>>(part, scal);
}

// Round 10
// 241.167 us; speedup vs baseline: 1.2426x; 1.0081x over previous
//
#include <hip/hip_runtime.h>
#include <hip/hip_fp16.h>
#include <math.h>

#define N_NODES 100000
#define N_EDGES 1200000
#define SLOTS   48                              // Poisson(12): P(any deg>48) ~ 3e-10
#define HEAD_BLOCKS ((N_NODES + 63) / 64)       // L2/L3 grid: 1563 blocks, 64 nodes
#define L1_BLOCKS  ((N_NODES + 255) / 256)      // L1 grid: 391 blocks, 256 nodes

// bucketed adjacency build (R19)
#define BNODES 256                              // nodes per bucket (dst>>8)
#define NBUCK  ((N_NODES + BNODES - 1) / BNODES)   // 391
#define BCAP   3584                             // 9.3 sigma above mean 3070
#define CHUNK  4096                             // edges per partition block

typedef _Float16 half8_t __attribute__((ext_vector_type(8)));
typedef float    f32x4_t __attribute__((ext_vector_type(4)));

// ---------------------------------------------------------------- utilities

__device__ __forceinline__ float bcastf(float v, int l) {
    return __uint_as_float(__builtin_amdgcn_readlane(__float_as_uint(v), (unsigned)l));
}

__device__ __forceinline__ void accum8(float* m, const uint4& v) {
    const __half2* p = reinterpret_cast<const __half2*>(&v);
#pragma unroll
    for (int t = 0; t < 4; ++t) {
        const float2 f = __half22float2(p[t]);
        m[2 * t] += f.x; m[2 * t + 1] += f.y;
    }
}

__device__ __forceinline__ void accum4(float* m, const uint2& v) {
    const __half2* p = reinterpret_cast<const __half2*>(&v);
    const float2 f0 = __half22float2(p[0]);
    const float2 f1 = __half22float2(p[1]);
    m[0] += f0.x; m[1] += f0.y; m[2] += f1.x; m[3] += f1.y;
}

// x -> padded fp16 [N+1][8]; + cursor zero + h-buffer sentinel rows zero
__global__ __launch_bounds__(256) void convert_init(const float* __restrict__ x,
                                                    __half* __restrict__ x16,
                                                    unsigned* __restrict__ cursor,
                                                    __half* __restrict__ zA,
                                                    __half* __restrict__ zB) {
    const int gid = blockIdx.x * 256 + threadIdx.x;
    if (gid <= N_NODES) {
        __half h[8];
#pragma unroll
        for (int i = 0; i < 8; ++i) h[i] = __float2half(0.f);
        if (gid < N_NODES) {
#pragma unroll
            for (int i = 0; i < 5; ++i) h[i] = __float2half(x[gid * 5 + i]);
        }
        *reinterpret_cast<uint4*>(&x16[(size_t)gid * 8]) =
            *reinterpret_cast<const uint4*>(h);
    }
    if (gid < NBUCK) cursor[gid] = 0u;
    if (gid < 64) {
        zA[(size_t)N_NODES * 64 + gid] = __float2half(0.f);
        zB[(size_t)N_NODES * 64 + gid] = __float2half(0.f);
    }
}

// ---------------------------------------------------------------- adjacency build
// Pass 1: partition edges into dst-range buckets (LDS histogram -> one cursor
// reservation per (block,bucket) -> run appends). R19-proven.
__global__ __launch_bounds__(256) void edge_partition(const int* __restrict__ src,
                                                      const int* __restrict__ dst,
                                                      unsigned* __restrict__ cursor,
                                                      unsigned* __restrict__ packed) {
    __shared__ unsigned histL[NBUCK];
    __shared__ unsigned baseL[NBUCK];
    const int tid = threadIdx.x;
    const int e0 = blockIdx.x * CHUNK;
    for (int b = tid; b < NBUCK; b += 256) histL[b] = 0u;
    __syncthreads();
#pragma unroll
    for (int i = 0; i < CHUNK / 256; ++i) {
        const int e = e0 + i * 256 + tid;
        if (e < N_EDGES) atomicAdd(&histL[(unsigned)dst[e] >> 8], 1u);
    }
    __syncthreads();
    for (int b = tid; b < NBUCK; b += 256) {
        const unsigned c = histL[b];
        baseL[b] = c ? atomicAdd(&cursor[b], c) : 0u;
        histL[b] = 0u;                           // reuse as local position counter
    }
    __syncthreads();
#pragma unroll
    for (int i = 0; i < CHUNK / 256; ++i) {
        const int e = e0 + i * 256 + tid;
        if (e < N_EDGES) {
            const unsigned d = (unsigned)dst[e], s = (unsigned)src[e];
            const unsigned b = d >> 8;
            const unsigned r = atomicAdd(&histL[b], 1u);
            const unsigned pos = baseL[b] + r;
            if (pos < BCAP)                       // astronomically-rare overflow guard
                packed[(size_t)b * BCAP + pos] = ((d & 255u) << 17) | s;
        }
    }
}

// Pass 2: one block per bucket; slot rows built in LDS, streamed out coalesced.
__global__ __launch_bounds__(256) void bucket_build(const unsigned* __restrict__ packed,
                                                    const unsigned* __restrict__ cursor,
                                                    unsigned* __restrict__ slots,
                                                    unsigned* __restrict__ cnt,
                                                    float* __restrict__ invcnt) {
    __shared__ __align__(16) unsigned slotsL[BNODES * SLOTS];   // 48 KB
    __shared__ unsigned cntL[BNODES];
    const int tid = threadIdx.x;
    const int b = blockIdx.x;
    cntL[tid] = 0u;
    __syncthreads();
    const unsigned nE = min(cursor[b], (unsigned)BCAP);
    const unsigned* pb = packed + (size_t)b * BCAP;
    for (unsigned i = tid; i < nE; i += 256) {
        const unsigned p = pb[i];
        const unsigned dl = p >> 17;
        const unsigned r = atomicAdd(&cntL[dl], 1u);
        if (r < SLOTS) slotsL[dl * SLOTS + r] = p & 0x1FFFFu;
    }
    __syncthreads();
    const int nvalid = min(N_NODES - b * BNODES, BNODES);
    const uint4* sl4 = reinterpret_cast<const uint4*>(slotsL);
    uint4* sg4 = reinterpret_cast<uint4*>(slots) + (size_t)b * (BNODES * SLOTS / 4);
    const int l4 = nvalid * (SLOTS / 4);
    for (int i = tid; i < l4; i += 256) sg4[i] = sl4[i];
    if (tid < nvalid) {
        const int node = b * BNODES + tid;
        const unsigned c = cntL[tid];
        cnt[node] = c;
        invcnt[node] = 1.0f / (float)(c + 1u);   // +1 self loop
    }
}

// ---------------------------------------------------------------- weight folding
// V2 = W @ U_bot [IN,64];  cp = c + b @ U_bot [64]
template <int IN>
__global__ __launch_bounds__(256) void precompute_v(const float* __restrict__ W,
                                                    const float* __restrict__ b,
                                                    const float* __restrict__ U,
                                                    const float* __restrict__ c,
                                                    float* __restrict__ V2,
                                                    float* __restrict__ cp) {
    __shared__ float Ub[64 * 64];
    const int tid = threadIdx.x;
    for (int j = tid; j < 64 * 64; j += 256) Ub[j] = U[IN * 64 + j];
    __syncthreads();
    const int w = tid >> 6, lane = tid & 63;
    const int r = blockIdx.x * 4 + w;
    if (r > IN) return;
    const float wv = (r < IN) ? W[r * 64 + lane] : b[lane];
    float o = (r < IN) ? 0.f : c[lane];
#pragma unroll 8
    for (int k = 0; k < 64; ++k) o += bcastf(wv, k) * Ub[k * 64 + lane];
    if (r < IN) V2[r * 64 + lane] = o;
    else        cp[lane] = o;
}

// Interleaved-transposed fp16 weights: BT[col][k], k=2q -> Utop[q][col],
// k=2q+1 -> V2[q][col].
__global__ __launch_bounds__(64) void bt_build(const float* __restrict__ U1,
                                               const float* __restrict__ V2a,
                                               const float* __restrict__ U2,
                                               const float* __restrict__ V2b,
                                               const float* __restrict__ U3,
                                               const float* __restrict__ V2c,
                                               __half* __restrict__ BTa,
                                               __half* __restrict__ BTb,
                                               __half* __restrict__ BTc) {
    const int b = blockIdx.x, q = threadIdx.x;
    if (b < 64) {                                // L1: KPAD=32, IN=5
        const int col = b;
        if (q < 16) {
            __half2 v = __halves2half2(__float2half(0.f), __float2half(0.f));
            if (q < 5)
                v = __halves2half2(__float2half(U1[q * 64 + col]),
                                   __float2half(V2a[q * 64 + col]));
            *reinterpret_cast<__half2*>(&BTa[col * 32 + 2 * q]) = v;
        }
    } else if (b < 128) {                        // L2: KPAD=128, IN=64
        const int col = b - 64;
        const __half2 v = __halves2half2(__float2half(U2[q * 64 + col]),
                                         __float2half(V2b[q * 64 + col]));
        *reinterpret_cast<__half2*>(&BTb[col * 128 + 2 * q]) = v;
    } else {                                     // L3
        const int col = b - 128;
        const __half2 v = __halves2half2(__float2half(U3[q * 64 + col]),
                                         __float2half(V2c[q * 64 + col]));
        *reinterpret_cast<__half2*>(&BTc[col * 128 + 2 * q]) = v;
    }
}

// ---------------------------------------------------------------- layer 1 (IN=5)
// R20 packed-fp16 x gather, 2-lane groups, 4-deep.
__global__ __launch_bounds__(512, 6) void fused_layer8(
        const __half* __restrict__ x16,
        const unsigned* __restrict__ slots,
        const unsigned* __restrict__ cnt,
        const float* __restrict__ invcnt,
        const __half* __restrict__ BT16,         // [64][32]
        const float* __restrict__ cp,
        __half* __restrict__ hnextH) {
    __shared__ __align__(16) char Ab[256 * 64];  // 16 KB A-tile (K=32 fp16)

    const int tid  = threadIdx.x;
    const int wv   = __builtin_amdgcn_readfirstlane(tid >> 6);
    const int lane = tid & 63;
    const int g = lane >> 1, sub = lane & 1;
    const int nb = blockIdx.x * 256;
    const int r  = wv * 32 + g;
    const int n  = nb + r;
    const bool valid = n < N_NODES;

    const unsigned sent  = (unsigned)N_NODES;    // zeroed sentinel row
    const unsigned selfi = valid ? (unsigned)n : sent;
    const char* xb = reinterpret_cast<const char*>(x16);
    const uint2 hs = *reinterpret_cast<const uint2*>(xb + ((size_t)selfi << 4) + (sub << 3));
    float m[4];
    {
        const __half2* p = reinterpret_cast<const __half2*>(&hs);
        const float2 f0 = __half22float2(p[0]);
        const float2 f1 = __half22float2(p[1]);
        m[0] = f0.x; m[1] = f0.y; m[2] = f1.x; m[3] = f1.y;   // self loop
    }
    int deg = 0;
    if (valid) { deg = (int)cnt[n]; if (deg > SLOTS) deg = SLOTS; }
    int maxd = deg;                              // wave-uniform bound
#pragma unroll
    for (int off = 1; off < 64; off <<= 1)
        maxd = max(maxd, __shfl_xor(maxd, off));
    const unsigned* srow = slots + (size_t)(valid ? n : 0) * SLOTS;

    uint4 s4 = make_uint4(sent, sent, sent, sent);
    if (0 < deg) s4 = *reinterpret_cast<const uint4*>(srow);
    for (int j = 0; j < maxd; j += 4) {
        uint4 s4n = make_uint4(sent, sent, sent, sent);
        if (j + 4 < deg) s4n = *reinterpret_cast<const uint4*>(srow + j + 4);
        const unsigned i0 = (j + 0 < deg) ? s4.x : sent;
        const unsigned i1 = (j + 1 < deg) ? s4.y : sent;
        const unsigned i2 = (j + 2 < deg) ? s4.z : sent;
        const unsigned i3 = (j + 3 < deg) ? s4.w : sent;
        const uint2 v0 = *reinterpret_cast<const uint2*>(xb + ((size_t)i0 << 4) + (sub << 3));
        const uint2 v1 = *reinterpret_cast<const uint2*>(xb + ((size_t)i1 << 4) + (sub << 3));
        const uint2 v2 = *reinterpret_cast<const uint2*>(xb + ((size_t)i2 << 4) + (sub << 3));
        const uint2 v3 = *reinterpret_cast<const uint2*>(xb + ((size_t)i3 << 4) + (sub << 3));
        accum4(m, v0); accum4(m, v1); accum4(m, v2); accum4(m, v3);
        s4 = s4n;
    }
    const float ic = valid ? invcnt[n] : 0.f;
#pragma unroll
    for (int t = 0; t < 4; ++t) m[t] *= ic;

    // stage A row: halves k=2q -> hp_q, k=2q+1 -> m_q; k>=16 zeroed.
    {
        const unsigned* hw = reinterpret_cast<const unsigned*>(&hs);
        unsigned o[4];
#pragma unroll
        for (int t = 0; t < 2; ++t) {
            const __half2 mh = __float22half2_rn(make_float2(m[2 * t], m[2 * t + 1]));
            const unsigned mw = *reinterpret_cast<const unsigned*>(&mh);
            const unsigned hpw = hw[t];
            o[2 * t]     = (hpw & 0xFFFFu) | (mw << 16);
            o[2 * t + 1] = (hpw >> 16)     | (mw & 0xFFFF0000u);
        }
        const int swz = (r & 3) << 4;
        *reinterpret_cast<uint4*>(&Ab[r * 64 + ((sub * 16) ^ swz)]) =
            make_uint4(o[0], o[1], o[2], o[3]);
        *reinterpret_cast<uint4*>(&Ab[r * 64 + (((2 + sub) * 16) ^ swz)]) =
            make_uint4(0u, 0u, 0u, 0u);
    }

    // B-fragment from BT16 (one dwordx4 per thread)
    const int nt = wv & 3, mtb = wv >> 2;
    const int col = nt * 16 + (lane & 15);
    const half8_t bfrag = *reinterpret_cast<const half8_t*>(&BT16[col * 32 + ((lane >> 4) * 8)]);
    const float cpl = cp[col];
    __syncthreads();

    // MFMA: 8 tiles per wave (mt = mtb + 2t)
    const int rq = lane & 15, q4 = lane >> 4;
    f32x4_t acc[8];
#pragma unroll
    for (int t = 0; t < 8; ++t) {
        const int row = (mtb + 2 * t) * 16 + rq;
        const int cb  = (q4 * 16) ^ ((row & 3) << 4);
        const half8_t af = *reinterpret_cast<const half8_t*>(&Ab[row * 64 + cb]);
        f32x4_t z = {0.f, 0.f, 0.f, 0.f};
        acc[t] = __builtin_amdgcn_mfma_f32_16x16x32_f16(af, bfrag, z, 0, 0, 0);
    }
#pragma unroll
    for (int t = 0; t < 8; ++t) {
#pragma unroll
        for (int rr = 0; rr < 4; ++rr) {
            const int row  = (mtb + 2 * t) * 16 + q4 * 4 + rr;
            const int node = nb + row;
            if (node < N_NODES)
                hnextH[(size_t)node * 64 + col] =
                    __float2half(fmaxf(acc[t][rr] + cpl, 0.f));
        }
    }
}

// ---------------------------------------------------------------- layers 2/3 (IN=64)
// R18 packed gather + R20 BT16, 4-deep at (512,6) — the measured optimum.
// Bracketing experiment (R20 24wv x 4-deep = 96 outstanding/CU ~42us;
// R22 16wv x 8-deep = 128 outstanding ~44us; R21 spill-storm sustained
// 3.6 TB/s) => the gather is bound by the memory subsystem's random-128B
// service rate, not by wave-side MLP. Touched bytes (166 MB/layer) are
// algorithmically minimal. This config is the roofline operating point.
template <bool OUT16, bool HEADS>
__global__ __launch_bounds__(512, 6) void fused_layer64(
        const __half* __restrict__ hprevH,
        const unsigned* __restrict__ slots,
        const unsigned* __restrict__ cnt,
        const float* __restrict__ invcnt,
        const __half* __restrict__ BT16,         // [64][128]
        const float* __restrict__ cp,
        float* __restrict__ hnextF,
        __half* __restrict__ hnextH,
        const float* __restrict__ bs,  const float* __restrict__ bst,
        const float* __restrict__ bo,
        const float* __restrict__ Ws,  const float* __restrict__ Wst,
        const float* __restrict__ Wo,
        float* __restrict__ state, float* __restrict__ part) {
    __shared__ __align__(16) char Ab[64 * 256];          // 16 KB A-tile
    __shared__ float Hh[HEADS ? 64 * 64 : 8];            // 16 KB h stage (L3)
    __shared__ float Wl[HEADS ? 256 : 8];                // head weights f-major
    __shared__ float sgl[HEADS ? 64 : 8];
    __shared__ float ocl[HEADS ? 64 : 8];

    const int tid  = threadIdx.x;
    const int wv   = __builtin_amdgcn_readfirstlane(tid >> 6);
    const int lane = tid & 63;
    const int g = lane >> 3, sub = lane & 7;
    const int nb = blockIdx.x * 64;
    const int r  = wv * 8 + g;                           // block-local A row
    const int n  = nb + r;
    const bool valid = n < N_NODES;

    if constexpr (HEADS) {
        if (tid < 256) {
            const int f = tid >> 2, c = tid & 3;
            float w;
            if      (c == 0) w = Ws[f * 2];
            else if (c == 1) w = Ws[f * 2 + 1];
            else if (c == 2) w = Wst[f];
            else             w = Wo[f];
            Wl[tid] = w;
        }
    }

    // ---- packed gather-mean
    const unsigned sent  = (unsigned)N_NODES;            // zeroed sentinel row
    const unsigned selfi = valid ? (unsigned)n : sent;
    const char* hb = reinterpret_cast<const char*>(hprevH);
    const uint4 hs = *reinterpret_cast<const uint4*>(hb + ((size_t)selfi << 7) + (sub << 4));
    float m[8];
    {
        const __half2* p = reinterpret_cast<const __half2*>(&hs);
#pragma unroll
        for (int t = 0; t < 4; ++t) {
            const float2 f = __half22float2(p[t]);
            m[2 * t] = f.x; m[2 * t + 1] = f.y;          // self loop
        }
    }
    int deg = 0;
    if (valid) { deg = (int)cnt[n]; if (deg > SLOTS) deg = SLOTS; }
    int maxd = deg;                                      // wave-uniform bound
#pragma unroll
    for (int off = 8; off < 64; off <<= 1)
        maxd = max(maxd, __shfl_xor(maxd, off));
    const unsigned* srow = slots + (size_t)(valid ? n : 0) * SLOTS;

    uint4 s4 = make_uint4(sent, sent, sent, sent);
    if (0 < deg) s4 = *reinterpret_cast<const uint4*>(srow);
    for (int j = 0; j < maxd; j += 4) {
        uint4 s4n = make_uint4(sent, sent, sent, sent);  // prefetch next chunk
        if (j + 4 < deg) s4n = *reinterpret_cast<const uint4*>(srow + j + 4);
        const unsigned i0 = (j + 0 < deg) ? s4.x : sent;
        const unsigned i1 = (j + 1 < deg) ? s4.y : sent;
        const unsigned i2 = (j + 2 < deg) ? s4.z : sent;
        const unsigned i3 = (j + 3 < deg) ? s4.w : sent;
        const uint4 v0 = *reinterpret_cast<const uint4*>(hb + ((size_t)i0 << 7) + (sub << 4));
        const uint4 v1 = *reinterpret_cast<const uint4*>(hb + ((size_t)i1 << 7) + (sub << 4));
        const uint4 v2 = *reinterpret_cast<const uint4*>(hb + ((size_t)i2 << 7) + (sub << 4));
        const uint4 v3 = *reinterpret_cast<const uint4*>(hb + ((size_t)i3 << 7) + (sub << 4));
        accum8(m, v0); accum8(m, v1); accum8(m, v2); accum8(m, v3);
        s4 = s4n;
    }
    const float ic = valid ? invcnt[n] : 0.f;
#pragma unroll
    for (int t = 0; t < 8; ++t) m[t] *= ic;

    // interleave (hp, m) -> fp16 pairs, 2 swizzled b128 writes
    {
        unsigned out[8];
        const unsigned* hw = reinterpret_cast<const unsigned*>(&hs);
#pragma unroll
        for (int t = 0; t < 4; ++t) {
            const __half2 mh = __float22half2_rn(make_float2(m[2 * t], m[2 * t + 1]));
            const unsigned mw = *reinterpret_cast<const unsigned*>(&mh);
            const unsigned hpw = hw[t];
            out[2 * t]     = (hpw & 0xFFFFu) | (mw << 16);
            out[2 * t + 1] = (hpw >> 16)     | (mw & 0xFFFF0000u);
        }
        const int swz = (r & 7) << 4;
        uint4 lo = make_uint4(out[0], out[1], out[2], out[3]);
        uint4 hi = make_uint4(out[4], out[5], out[6], out[7]);
        *reinterpret_cast<uint4*>(&Ab[r * 256 + ((sub * 32)      ^ swz)]) = lo;
        *reinterpret_cast<uint4*>(&Ab[r * 256 + ((sub * 32 + 16) ^ swz)]) = hi;
    }

    // ---- B-fragments from BT16 (4 dwordx4 per thread; pre-barrier)
    const int nt = wv & 3, mt0 = wv >> 2;                // tiles (mt0,nt) and (mt0+2,nt)
    const int col = nt * 16 + (lane & 15);
    half8_t bfrag[4];
#pragma unroll
    for (int kt = 0; kt < 4; ++kt)
        bfrag[kt] = *reinterpret_cast<const half8_t*>(
            &BT16[col * 128 + kt * 32 + ((lane >> 4) * 8)]);
    const float cpl = cp[col];
    __syncthreads();

    // ---- MFMA phase: 2 tiles per wave, shared bfrag
    f32x4_t acc0 = {0.f, 0.f, 0.f, 0.f};
    f32x4_t acc1 = {0.f, 0.f, 0.f, 0.f};
    const int rq = lane & 15, q16 = (lane >> 4) * 16;
#pragma unroll
    for (int kt = 0; kt < 4; ++kt) {
        const int row0 = mt0 * 16 + rq;
        const int row1 = row0 + 32;
        const int cb   = kt * 64 + q16;
        const int swz  = (row0 & 7) << 4;                // row1&7 == row0&7
        const half8_t a0 = *reinterpret_cast<const half8_t*>(&Ab[row0 * 256 + (cb ^ swz)]);
        const half8_t a1 = *reinterpret_cast<const half8_t*>(&Ab[row1 * 256 + (cb ^ swz)]);
        acc0 = __builtin_amdgcn_mfma_f32_16x16x32_f16(a0, bfrag[kt], acc0, 0, 0, 0);
        acc1 = __builtin_amdgcn_mfma_f32_16x16x32_f16(a1, bfrag[kt], acc1, 0, 0, 0);
    }

    // ---- epilogue: bias + relu + store
#pragma unroll
    for (int t = 0; t < 4; ++t) {
        const int row  = mt0 * 16 + ((lane >> 4) * 4) + t;
        const int node = nb + row;
        const float h  = fmaxf(acc0[t] + cpl, 0.f);
        if (node < N_NODES) {
            if constexpr (OUT16) hnextH[(size_t)node * 64 + col] = __float2half(h);
            else                 hnextF[(size_t)node * 64 + col] = h;
        }
        if constexpr (HEADS) Hh[row * 64 + col] = h;
    }
#pragma unroll
    for (int t = 0; t < 4; ++t) {
        const int row  = (mt0 + 2) * 16 + ((lane >> 4) * 4) + t;
        const int node = nb + row;
        const float h  = fmaxf(acc1[t] + cpl, 0.f);
        if (node < N_NODES) {
            if constexpr (OUT16) hnextH[(size_t)node * 64 + col] = __float2half(h);
            else                 hnextF[(size_t)node * 64 + col] = h;
        }
        if constexpr (HEADS) Hh[row * 64 + col] = h;
    }

    // ---- fused heads (layer 3): 8 threads per node
    if constexpr (HEADS) {
        __syncthreads();
        const int nl = tid >> 3, sb2 = tid & 7;
        const float4 h0 = *reinterpret_cast<const float4*>(&Hh[nl * 64 + sb2 * 8]);
        const float4 h1 = *reinterpret_cast<const float4*>(&Hh[nl * 64 + sb2 * 8 + 4]);
        float r0 = 0.f, r1 = 0.f, r2 = 0.f, r3 = 0.f;
        const float hv[8] = {h0.x, h0.y, h0.z, h0.w, h1.x, h1.y, h1.z, h1.w};
#pragma unroll
        for (int t = 0; t < 8; ++t) {
            const float4 w = *reinterpret_cast<const float4*>(&Wl[(sb2 * 8 + t) * 4]);
            r0 += hv[t] * w.x; r1 += hv[t] * w.y; r2 += hv[t] * w.z; r3 += hv[t] * w.w;
        }
#pragma unroll
        for (int off = 1; off < 8; off <<= 1) {
            r0 += __shfl_xor(r0, off); r1 += __shfl_xor(r1, off);
            r2 += __shfl_xor(r2, off); r3 += __shfl_xor(r3, off);
        }
        if (sb2 == 0) {
            const int node = nb + nl;
            float sg = 0.f, oc = 0.f;
            if (node < N_NODES) {
                state[(size_t)node * 2 + 0] = r0 + bs[0];
                state[(size_t)node * 2 + 1] = r1 + bs[1];
                sg = 1.0f / (1.0f + __expf(-(r2 + bst[0])));
                oc = r3 + bo[0];
            }
            sgl[nl] = sg; ocl[nl] = oc;
        }
        __syncthreads();
        if (tid < 64) {
            float a = sgl[tid], b = ocl[tid];
#pragma unroll
            for (int off = 1; off < 64; off <<= 1) {
                a += __shfl_xor(a, off); b += __shfl_xor(b, off);
            }
            if (tid == 0) {
                part[blockIdx.x * 2 + 0] = a;
                part[blockIdx.x * 2 + 1] = b;
            }
        }
    }
}

// ---------------------------------------------------------------- final reduce

__global__ __launch_bounds__(1024) void final_reduce(const float* __restrict__ part,
                                                     float* __restrict__ scal) {
    __shared__ float l0[1024], l1[1024];
    const int t = threadIdx.x;
    float a = 0.f, b = 0.f;
    for (int i = t; i < HEAD_BLOCKS; i += 1024) { a += part[2 * i]; b += part[2 * i + 1]; }
    l0[t] = a; l1[t] = b;
    __syncthreads();
    for (int off = 512; off; off >>= 1) {
        if (t < off) { l0[t] += l0[t + off]; l1[t] += l1[t + off]; }
        __syncthreads();
    }
    if (t == 0) {
        scal[0] = l0[0] / (float)N_NODES;   // stability
        scal[1] = l1[0] / (float)N_NODES;   // opf_cost
    }
}

// ---------------------------------------------------------------- launch

extern "C" void kernel_launch(void* const* d_in, const int* in_sizes, int n_in,
                              void* d_out, int out_size, void* d_ws, size_t ws_size,
                              hipStream_t stream) {
    const float* x   = (const float*)d_in[0];
    const int*   ei  = (const int*)d_in[1];
    const float* W1  = (const float*)d_in[2];
    const float* b1  = (const float*)d_in[3];
    const float* U1  = (const float*)d_in[4];
    const float* c1  = (const float*)d_in[5];
    const float* W2  = (const float*)d_in[6];
    const float* b2  = (const float*)d_in[7];
    const float* U2  = (const float*)d_in[8];
    const float* c2  = (const float*)d_in[9];
    const float* W3  = (const float*)d_in[10];
    const float* b3  = (const float*)d_in[11];
    const float* U3  = (const float*)d_in[12];
    const float* c3  = (const float*)d_in[13];
    const float* Ws  = (const float*)d_in[14];
    const float* bs  = (const float*)d_in[15];
    const float* Wst = (const float*)d_in[16];
    const float* bst = (const float*)d_in[17];
    const float* Wo  = (const float*)d_in[18];
    const float* bo  = (const float*)d_in[19];

    const int* src = ei;              // edge_index[0]
    const int* dst = ei + N_EDGES;    // edge_index[1]

    char* wsp = (char*)d_ws;
    size_t off = 0;
    auto alloc = [&](size_t bytes) -> char* {
        char* p = wsp + off;
        off = (off + bytes + 255) & ~(size_t)255;
        return p;
    };
    unsigned* cnt    = (unsigned*)alloc((size_t)N_NODES * 4);
    float*    invcnt = (float*)   alloc((size_t)N_NODES * 4);
    float*    part   = (float*)   alloc((size_t)HEAD_BLOCKS * 2 * 4);
    unsigned* cursor = (unsigned*)alloc((size_t)NBUCK * 4);
    float*    V2a    = (float*)   alloc((size_t)5 * 64 * 4);
    float*    V2b    = (float*)   alloc((size_t)64 * 64 * 4);
    float*    V2c    = (float*)   alloc((size_t)64 * 64 * 4);
    float*    cpa    = (float*)   alloc((size_t)64 * 4);
    float*    cpb    = (float*)   alloc((size_t)64 * 4);
    float*    cpc    = (float*)   alloc((size_t)64 * 4);
    __half*   BTa    = (__half*)  alloc((size_t)64 * 32 * 2);
    __half*   BTb    = (__half*)  alloc((size_t)64 * 128 * 2);
    __half*   BTc    = (__half*)  alloc((size_t)64 * 128 * 2);
    __half*   x16    = (__half*)  alloc(((size_t)N_NODES + 1) * 8 * 2);   // padded x + sentinel
    unsigned* slots  = (unsigned*)alloc((size_t)N_NODES * SLOTS * 4);     // 19.2 MB
    __half*   h16A   = (__half*)  alloc(((size_t)N_NODES + 1) * 64 * 2);  // +sentinel row
    __half*   h16B   = (__half*)  alloc(((size_t)N_NODES + 1) * 64 * 2);
    // packed edge buckets (5.6 MB) alias h16B: dead until layer-2 writes h16B.
    unsigned* packed = (unsigned*)h16B;

    float* out   = (float*)d_out;
    float* state = out;                 // [N, 2]
    float* scal  = out + 200000;        // stability, opf_cost
    float* hout  = out + 200002;        // [N, 64]

    const int PB = (N_EDGES + CHUNK - 1) / CHUNK;   // 293

    // weight folding (graph-independent)
    precompute_v<5> <<<2, 256, 0, stream>>>(W1, b1, U1, c1, V2a, cpa);
    precompute_v<64><<<17, 256, 0, stream>>>(W2, b2, U2, c2, V2b, cpb);
    precompute_v<64><<<17, 256, 0, stream>>>(W3, b3, U3, c3, V2c, cpc);
    bt_build<<<192, 64, 0, stream>>>(U1, V2a, U2, V2b, U3, V2c, BTa, BTb, BTc);

    // x16 convert + cursor/sentinel init, then bucketed adjacency build
    convert_init<<<L1_BLOCKS, 256, 0, stream>>>(x, x16, cursor, h16A, h16B);
    edge_partition<<<PB, 256, 0, stream>>>(src, dst, cursor, packed);
    bucket_build<<<NBUCK, 256, 0, stream>>>(packed, cursor, slots, cnt, invcnt);

    // L1: packed fp16 x gather (256-node blocks)
    fused_layer8<<<L1_BLOCKS, 512, 0, stream>>>(
        x16, slots, cnt, invcnt, BTa, cpa, h16A);
    // L2/L3: packed-gather 64-node blocks
    fused_layer64<true, false><<<HEAD_BLOCKS, 512, 0, stream>>>(
        h16A, slots, cnt, invcnt, BTb, cpb, nullptr, h16B,
        nullptr, nullptr, nullptr, nullptr, nullptr, nullptr, nullptr, nullptr);
    fused_layer64<false, true><<<HEAD_BLOCKS, 512, 0, stream>>>(
        h16B, slots, cnt, invcnt, BTc, cpc, hout, nullptr,
        bs, bst, bo, Ws, Wst, Wo, state, part);
    final_reduce<<<1, 1024, 0, stream>>>(part, scal);
}